// Round 6
// baseline (127.728 us; speedup 1.0000x reference)
//
#include <hip/hip_runtime.h>
#include <math.h>

// Problem constants (fixed by the reference setup)
constexpr int Bb = 32;
constexpr int Ss = 2048;
constexpr int Hh = 1024;
constexpr int SC = 64;                 // s-rows per block in fused kernel
constexpr int CPB = Ss / SC;           // 32 chunks per batch
constexpr int NBLK = Bb * CPB;         // 1024 blocks (4 blocks/CU, one round)

// ---------------- Kernel A: h = hidden @ W_in^T ----------------
// Block = (output index i, group of 4 batches). i = blk & 1023 so the 8 blocks
// sharing W row i are 1024 apart -> same XCD -> W row fetched from HBM once.
__global__ __launch_bounds__(256) void gemv_h_kernel(const float* __restrict__ hidden,
                                                     const float* __restrict__ W,
                                                     float* __restrict__ h)
{
    int tid  = threadIdx.x;
    int wave = tid >> 6;
    int lane = tid & 63;
    int i  = blockIdx.x & (Hh - 1);    // 0..1023
    int bg = blockIdx.x >> 10;         // 0..7
    int b  = bg * 4 + wave;            // 0..31
    const float4* wr = reinterpret_cast<const float4*>(W + (size_t)i * Hh);
    const float4* hd = reinterpret_cast<const float4*>(hidden + (size_t)b * Hh);
    float d = 0.f;
#pragma unroll
    for (int k = 0; k < 4; ++k) {
        float4 wv = wr[lane + 64 * k];
        float4 hv = hd[lane + 64 * k];
        d += wv.x * hv.x + wv.y * hv.y + wv.z * hv.z + wv.w * hv.w;
    }
#pragma unroll
    for (int off = 32; off > 0; off >>= 1) d += __shfl_xor(d, off, 64);
    if (lane == 0) h[(size_t)b * Hh + i] = d;
}

// ---------------- Kernel B: fused scores + online softmax + partial context ----
// Block = (batch b, chunk of SC=64 rows). 4 waves x 16 rows, processed as 8
// PAIRS with ping-pong register prefetch (2 rows = 8 float4 = 32 VGPR per
// buffer). VGPR capped at 128 via __launch_bounds__(256,4) -> 4 waves/SIMD:
// twice the independent issue streams to cover each wave's serial
// dot -> shuffle-reduce -> exp -> ctx chain.
__global__ __launch_bounds__(256, 4) void attn_partial_kernel(const float* __restrict__ enc,
                                                              const float* __restrict__ h,
                                                              float* __restrict__ scores,
                                                              float* __restrict__ pm,
                                                              float* __restrict__ pl,
                                                              float* __restrict__ pctx)
{
    int blk   = blockIdx.x;           // 0..NBLK-1
    int b     = blk >> 5;             // / CPB (CPB = 32)
    int chunk = blk & (CPB - 1);
    int s0    = chunk * SC;
    int tid   = threadIdx.x;
    int wave  = tid >> 6;
    int lane  = tid & 63;

    // h fragment for this lane (elements 4*lane + 256*k)
    float4 hf[4];
    const float4* h4 = reinterpret_cast<const float4*>(h + (size_t)b * Hh);
#pragma unroll
    for (int k = 0; k < 4; ++k) hf[k] = h4[lane + 64 * k];

    float m = -INFINITY;
    float l = 0.f;
    float4 ctx[4];
#pragma unroll
    for (int k = 0; k < 4; ++k) ctx[k] = make_float4(0.f, 0.f, 0.f, 0.f);

    const float4* ebase = reinterpret_cast<const float4*>(enc + ((size_t)b * Ss + s0 + wave * 16) * Hh);

#define LOADP(EV, P)                                                        \
    {                                                                       \
        _Pragma("unroll")                                                   \
        for (int r = 0; r < 2; ++r) {                                       \
            const float4* e4 = ebase + (size_t)((P) * 2 + r) * (Hh / 4);    \
            _Pragma("unroll")                                               \
            for (int k = 0; k < 4; ++k) EV[r][k] = e4[lane + 64 * k];       \
        }                                                                   \
    }

#define COMPP(EV, P)                                                        \
    {                                                                       \
        float d0 = 0.f, d1 = 0.f;                                           \
        _Pragma("unroll")                                                   \
        for (int k = 0; k < 4; ++k) {                                       \
            d0 += EV[0][k].x * hf[k].x + EV[0][k].y * hf[k].y +             \
                  EV[0][k].z * hf[k].z + EV[0][k].w * hf[k].w;              \
            d1 += EV[1][k].x * hf[k].x + EV[1][k].y * hf[k].y +             \
                  EV[1][k].z * hf[k].z + EV[1][k].w * hf[k].w;              \
        }                                                                   \
        _Pragma("unroll")                                                   \
        for (int off = 32; off > 0; off >>= 1) {                            \
            d0 += __shfl_xor(d0, off, 64);                                  \
            d1 += __shfl_xor(d1, off, 64);                                  \
        }                                                                   \
        if (lane == 0) {                                                    \
            *reinterpret_cast<float2*>(scores + (size_t)b * Ss + s0 +       \
                                       wave * 16 + 2 * (P)) =               \
                make_float2(d0, d1);                                        \
        }                                                                   \
        float mn = fmaxf(fmaxf(d0, d1), m);                                 \
        if (mn > m) {                                                       \
            float c = __expf(m - mn);                                       \
            l *= c;                                                         \
            _Pragma("unroll")                                               \
            for (int k = 0; k < 4; ++k) {                                   \
                ctx[k].x *= c; ctx[k].y *= c; ctx[k].z *= c; ctx[k].w *= c; \
            }                                                               \
            m = mn;                                                         \
        }                                                                   \
        float p0 = __expf(d0 - m);                                          \
        float p1 = __expf(d1 - m);                                          \
        l += p0 + p1;                                                       \
        _Pragma("unroll")                                                   \
        for (int k = 0; k < 4; ++k) {                                       \
            ctx[k].x += p0 * EV[0][k].x + p1 * EV[1][k].x;                  \
            ctx[k].y += p0 * EV[0][k].y + p1 * EV[1][k].y;                  \
            ctx[k].z += p0 * EV[0][k].z + p1 * EV[1][k].z;                  \
            ctx[k].w += p0 * EV[0][k].w + p1 * EV[1][k].w;                  \
        }                                                                   \
    }

    float4 evA[2][4], evB[2][4];
    LOADP(evA, 0);
#pragma unroll 1
    for (int qq = 0; qq < 3; ++qq) {
        LOADP(evB, 2 * qq + 1);
        COMPP(evA, 2 * qq);
        LOADP(evA, 2 * qq + 2);
        COMPP(evB, 2 * qq + 1);
    }
    LOADP(evB, 7);
    COMPP(evA, 6);
    COMPP(evB, 7);
#undef LOADP
#undef COMPP

    // intra-block combine across 4 waves via LDS
    __shared__ float lds_ctx[4][Hh];   // 16 KiB
    __shared__ float lds_m[4], lds_l[4];
    float4* ldsrow = reinterpret_cast<float4*>(lds_ctx[wave]);
#pragma unroll
    for (int k = 0; k < 4; ++k) ldsrow[64 * k + lane] = ctx[k];
    if (lane == 0) { lds_m[wave] = m; lds_l[wave] = l; }
    __syncthreads();

    float M = fmaxf(fmaxf(lds_m[0], lds_m[1]), fmaxf(lds_m[2], lds_m[3]));
    float L = 0.f;
    float4 acc = make_float4(0.f, 0.f, 0.f, 0.f);
#pragma unroll
    for (int w = 0; w < 4; ++w) {
        float c = __expf(lds_m[w] - M);
        L += c * lds_l[w];
        float4 v = reinterpret_cast<float4*>(lds_ctx[w])[tid];
        acc.x += c * v.x; acc.y += c * v.y; acc.z += c * v.z; acc.w += c * v.w;
    }
    reinterpret_cast<float4*>(pctx + (size_t)blk * Hh)[tid] = acc;
    if (tid == 0) { pm[blk] = M; pl[blk] = L; }
}

// ---------------- Kernel CD: combine partials -> context, scores -> attn_w ----
// Blocks [0,128): combine (b = blk>>2, 256-wide H slice). Blocks [128,384):
// finish attn_w; every thread recomputes (M,L) from pm/pl (L2 broadcast, cheap)
// so there is no cross-block dependency.
__global__ __launch_bounds__(256) void combine_finish_kernel(const float* __restrict__ pm,
                                                             const float* __restrict__ pl,
                                                             const float* __restrict__ pctx,
                                                             const float* __restrict__ scores,
                                                             float* __restrict__ out_ctx,
                                                             float* __restrict__ attn_out)
{
    int blk = blockIdx.x;
    int tid = threadIdx.x;
    if (blk < 128) {
        int b = blk >> 2;
        int col = (blk & 3) * 256 + tid;
        const float* mrow = pm + (size_t)b * CPB;
        const float* lrow = pl + (size_t)b * CPB;
        float M = -INFINITY;
#pragma unroll
        for (int c = 0; c < CPB; ++c) M = fmaxf(M, mrow[c]);
        float e[CPB];
        float L = 0.f;
#pragma unroll
        for (int c = 0; c < CPB; ++c) {
            e[c] = __expf(mrow[c] - M);
            L += e[c] * lrow[c];
        }
        float acc = 0.f;
#pragma unroll 4
        for (int c = 0; c < CPB; ++c)
            acc += e[c] * pctx[((size_t)b * CPB + c) * Hh + col];
        out_ctx[(size_t)b * Hh + col] = acc / L;
    } else {
        int idx = (blk - 128) * 256 + tid;   // 0..B*S-1
        int b = idx >> 11;                   // / S
        const float* mrow = pm + (size_t)b * CPB;
        const float* lrow = pl + (size_t)b * CPB;
        float M = -INFINITY;
#pragma unroll
        for (int c = 0; c < CPB; ++c) M = fmaxf(M, mrow[c]);
        float L = 0.f;
#pragma unroll
        for (int c = 0; c < CPB; ++c) L += __expf(mrow[c] - M) * lrow[c];
        attn_out[idx] = __expf(scores[idx] - M) / L;
    }
}

extern "C" void kernel_launch(void* const* d_in, const int* in_sizes, int n_in,
                              void* d_out, int out_size, void* d_ws, size_t ws_size,
                              hipStream_t stream) {
    const float* hidden = (const float*)d_in[0];   // [B,H]
    const float* enc    = (const float*)d_in[1];   // [B,S,H]
    const float* W_in   = (const float*)d_in[2];   // [H,H]

    float* out_ctx  = (float*)d_out;               // [B,H]   context first
    float* out_attn = (float*)d_out + Bb * Hh;     // [B,S]

    float* ws     = (float*)d_ws;
    float* h      = ws;                            // B*H      = 32768
    float* scores = ws + 32768;                    // B*S      = 65536
    float* pm     = ws + 98304;                    // NBLK     = 1024
    float* pl     = ws + 99328;                    // NBLK     = 1024
    float* pctx   = ws + 100352;                   // NBLK*H   = 1048576
    (void)in_sizes; (void)n_in; (void)out_size; (void)ws_size;

    // A: h = hidden @ W_in^T   (XCD-local W-row reuse)
    gemv_h_kernel<<<Hh * (Bb / 4), 256, 0, stream>>>(hidden, W_in, h);
    // B: fused scores + online softmax + partial context (single enc pass,
    //    pair ping-pong prefetch, 4 waves/SIMD)
    attn_partial_kernel<<<NBLK, 256, 0, stream>>>(enc, h, scores, pm, pl, pctx);
    // CD: combine -> context, and scores -> attn_w (no cross-block dependency)
    combine_finish_kernel<<<128 + (Bb * Ss) / 256, 256, 0, stream>>>(pm, pl, pctx, scores,
                                                                     out_ctx, out_attn);
}

// Round 7
// 61.899 us; speedup vs baseline: 2.0635x; 2.0635x over previous
//
#include <hip/hip_runtime.h>
#include <math.h>

// Problem constants (fixed by the reference setup)
constexpr int Bb = 32;
constexpr int Ss = 2048;
constexpr int Hh = 1024;
constexpr int SC = 64;                 // s-rows per block in fused kernel
constexpr int CPB = Ss / SC;           // 32 chunks per batch
constexpr int NBLK = Bb * CPB;         // 1024 blocks

// ---------------- Kernel A: h = hidden @ W_in^T ----------------
// Block = (output index i, group of 4 batches). i = blk & 1023 so the 8 blocks
// sharing W row i are 1024 apart -> same XCD -> W row fetched from HBM once.
__global__ __launch_bounds__(256) void gemv_h_kernel(const float* __restrict__ hidden,
                                                     const float* __restrict__ W,
                                                     float* __restrict__ h)
{
    int tid  = threadIdx.x;
    int wave = tid >> 6;
    int lane = tid & 63;
    int i  = blockIdx.x & (Hh - 1);    // 0..1023
    int bg = blockIdx.x >> 10;         // 0..7
    int b  = bg * 4 + wave;            // 0..31
    const float4* wr = reinterpret_cast<const float4*>(W + (size_t)i * Hh);
    const float4* hd = reinterpret_cast<const float4*>(hidden + (size_t)b * Hh);
    float d = 0.f;
#pragma unroll
    for (int k = 0; k < 4; ++k) {
        float4 wv = wr[lane + 64 * k];
        float4 hv = hd[lane + 64 * k];
        d += wv.x * hv.x + wv.y * hv.y + wv.z * hv.z + wv.w * hv.w;
    }
#pragma unroll
    for (int off = 32; off > 0; off >>= 1) d += __shfl_xor(d, off, 64);
    if (lane == 0) h[(size_t)b * Hh + i] = d;
}

// ---------------- Kernel B: fused scores + online softmax + partial context ----
// Block = (batch b, chunk of SC=64 rows). 4 waves x 16 rows, processed as 8
// PAIRS with ping-pong register prefetch (2 rows = 8 float4 = 32 VGPR per
// buffer). NO min-waves clamp: natural VGPR (~140) -> 3 waves/SIMD spill-free
// (R6's __launch_bounds__(256,4) cap forced spills in the hot loop: 128 < live
// set ~150 -> scratch round-trips -> 2.1x regression).
__global__ __launch_bounds__(256) void attn_partial_kernel(const float* __restrict__ enc,
                                                           const float* __restrict__ h,
                                                           float* __restrict__ scores,
                                                           float* __restrict__ pm,
                                                           float* __restrict__ pl,
                                                           float* __restrict__ pctx)
{
    int blk   = blockIdx.x;           // 0..NBLK-1
    int b     = blk >> 5;             // / CPB (CPB = 32)
    int chunk = blk & (CPB - 1);
    int s0    = chunk * SC;
    int tid   = threadIdx.x;
    int wave  = tid >> 6;
    int lane  = tid & 63;

    // h fragment for this lane (elements 4*lane + 256*k)
    float4 hf[4];
    const float4* h4 = reinterpret_cast<const float4*>(h + (size_t)b * Hh);
#pragma unroll
    for (int k = 0; k < 4; ++k) hf[k] = h4[lane + 64 * k];

    float m = -INFINITY;
    float l = 0.f;
    float4 ctx[4];
#pragma unroll
    for (int k = 0; k < 4; ++k) ctx[k] = make_float4(0.f, 0.f, 0.f, 0.f);

    const float4* ebase = reinterpret_cast<const float4*>(enc + ((size_t)b * Ss + s0 + wave * 16) * Hh);

#define LOADP(EV, P)                                                        \
    {                                                                       \
        _Pragma("unroll")                                                   \
        for (int r = 0; r < 2; ++r) {                                       \
            const float4* e4 = ebase + (size_t)((P) * 2 + r) * (Hh / 4);    \
            _Pragma("unroll")                                               \
            for (int k = 0; k < 4; ++k) EV[r][k] = e4[lane + 64 * k];       \
        }                                                                   \
    }

#define COMPP(EV, P)                                                        \
    {                                                                       \
        float d0 = 0.f, d1 = 0.f;                                           \
        _Pragma("unroll")                                                   \
        for (int k = 0; k < 4; ++k) {                                       \
            d0 += EV[0][k].x * hf[k].x + EV[0][k].y * hf[k].y +             \
                  EV[0][k].z * hf[k].z + EV[0][k].w * hf[k].w;              \
            d1 += EV[1][k].x * hf[k].x + EV[1][k].y * hf[k].y +             \
                  EV[1][k].z * hf[k].z + EV[1][k].w * hf[k].w;              \
        }                                                                   \
        _Pragma("unroll")                                                   \
        for (int off = 32; off > 0; off >>= 1) {                            \
            d0 += __shfl_xor(d0, off, 64);                                  \
            d1 += __shfl_xor(d1, off, 64);                                  \
        }                                                                   \
        if (lane == 0) {                                                    \
            *reinterpret_cast<float2*>(scores + (size_t)b * Ss + s0 +       \
                                       wave * 16 + 2 * (P)) =               \
                make_float2(d0, d1);                                        \
        }                                                                   \
        float mn = fmaxf(fmaxf(d0, d1), m);                                 \
        if (mn > m) {                                                       \
            float c = __expf(m - mn);                                       \
            l *= c;                                                         \
            _Pragma("unroll")                                               \
            for (int k = 0; k < 4; ++k) {                                   \
                ctx[k].x *= c; ctx[k].y *= c; ctx[k].z *= c; ctx[k].w *= c; \
            }                                                               \
            m = mn;                                                         \
        }                                                                   \
        float p0 = __expf(d0 - m);                                          \
        float p1 = __expf(d1 - m);                                          \
        l += p0 + p1;                                                       \
        _Pragma("unroll")                                                   \
        for (int k = 0; k < 4; ++k) {                                       \
            ctx[k].x += p0 * EV[0][k].x + p1 * EV[1][k].x;                  \
            ctx[k].y += p0 * EV[0][k].y + p1 * EV[1][k].y;                  \
            ctx[k].z += p0 * EV[0][k].z + p1 * EV[1][k].z;                  \
            ctx[k].w += p0 * EV[0][k].w + p1 * EV[1][k].w;                  \
        }                                                                   \
    }

    float4 evA[2][4], evB[2][4];
    LOADP(evA, 0);
#pragma unroll 1
    for (int qq = 0; qq < 3; ++qq) {
        LOADP(evB, 2 * qq + 1);
        COMPP(evA, 2 * qq);
        LOADP(evA, 2 * qq + 2);
        COMPP(evB, 2 * qq + 1);
    }
    LOADP(evB, 7);
    COMPP(evA, 6);
    COMPP(evB, 7);
#undef LOADP
#undef COMPP

    // intra-block combine across 4 waves via LDS
    __shared__ float lds_ctx[4][Hh];   // 16 KiB
    __shared__ float lds_m[4], lds_l[4];
    float4* ldsrow = reinterpret_cast<float4*>(lds_ctx[wave]);
#pragma unroll
    for (int k = 0; k < 4; ++k) ldsrow[64 * k + lane] = ctx[k];
    if (lane == 0) { lds_m[wave] = m; lds_l[wave] = l; }
    __syncthreads();

    float M = fmaxf(fmaxf(lds_m[0], lds_m[1]), fmaxf(lds_m[2], lds_m[3]));
    float L = 0.f;
    float4 acc = make_float4(0.f, 0.f, 0.f, 0.f);
#pragma unroll
    for (int w = 0; w < 4; ++w) {
        float c = __expf(lds_m[w] - M);
        L += c * lds_l[w];
        float4 v = reinterpret_cast<float4*>(lds_ctx[w])[tid];
        acc.x += c * v.x; acc.y += c * v.y; acc.z += c * v.z; acc.w += c * v.w;
    }
    reinterpret_cast<float4*>(pctx + (size_t)blk * Hh)[tid] = acc;
    if (tid == 0) { pm[blk] = M; pl[blk] = L; }
}

// ---------------- Kernel CD: combine partials -> context, scores -> attn_w ----
// Blocks [0,128): combine (b = blk>>2, 256-wide H slice). Blocks [128,384):
// finish attn_w; every thread recomputes (M,L) from pm/pl (L2 broadcast, cheap)
// so there is no cross-block dependency.
__global__ __launch_bounds__(256) void combine_finish_kernel(const float* __restrict__ pm,
                                                             const float* __restrict__ pl,
                                                             const float* __restrict__ pctx,
                                                             const float* __restrict__ scores,
                                                             float* __restrict__ out_ctx,
                                                             float* __restrict__ attn_out)
{
    int blk = blockIdx.x;
    int tid = threadIdx.x;
    if (blk < 128) {
        int b = blk >> 2;
        int col = (blk & 3) * 256 + tid;
        const float* mrow = pm + (size_t)b * CPB;
        const float* lrow = pl + (size_t)b * CPB;
        float M = -INFINITY;
#pragma unroll
        for (int c = 0; c < CPB; ++c) M = fmaxf(M, mrow[c]);
        float e[CPB];
        float L = 0.f;
#pragma unroll
        for (int c = 0; c < CPB; ++c) {
            e[c] = __expf(mrow[c] - M);
            L += e[c] * lrow[c];
        }
        float acc = 0.f;
#pragma unroll 4
        for (int c = 0; c < CPB; ++c)
            acc += e[c] * pctx[((size_t)b * CPB + c) * Hh + col];
        out_ctx[(size_t)b * Hh + col] = acc / L;
    } else {
        int idx = (blk - 128) * 256 + tid;   // 0..B*S-1
        int b = idx >> 11;                   // / S
        const float* mrow = pm + (size_t)b * CPB;
        const float* lrow = pl + (size_t)b * CPB;
        float M = -INFINITY;
#pragma unroll
        for (int c = 0; c < CPB; ++c) M = fmaxf(M, mrow[c]);
        float L = 0.f;
#pragma unroll
        for (int c = 0; c < CPB; ++c) L += __expf(mrow[c] - M) * lrow[c];
        attn_out[idx] = __expf(scores[idx] - M) / L;
    }
}

extern "C" void kernel_launch(void* const* d_in, const int* in_sizes, int n_in,
                              void* d_out, int out_size, void* d_ws, size_t ws_size,
                              hipStream_t stream) {
    const float* hidden = (const float*)d_in[0];   // [B,H]
    const float* enc    = (const float*)d_in[1];   // [B,S,H]
    const float* W_in   = (const float*)d_in[2];   // [H,H]

    float* out_ctx  = (float*)d_out;               // [B,H]   context first
    float* out_attn = (float*)d_out + Bb * Hh;     // [B,S]

    float* ws     = (float*)d_ws;
    float* h      = ws;                            // B*H      = 32768
    float* scores = ws + 32768;                    // B*S      = 65536
    float* pm     = ws + 98304;                    // NBLK     = 1024
    float* pl     = ws + 99328;                    // NBLK     = 1024
    float* pctx   = ws + 100352;                   // NBLK*H   = 1048576
    (void)in_sizes; (void)n_in; (void)out_size; (void)ws_size;

    // A: h = hidden @ W_in^T   (XCD-local W-row reuse)
    gemv_h_kernel<<<Hh * (Bb / 4), 256, 0, stream>>>(hidden, W_in, h);
    // B: fused scores + online softmax + partial context (single enc pass,
    //    pair ping-pong prefetch, natural VGPR -> 3 waves/SIMD, no spills)
    attn_partial_kernel<<<NBLK, 256, 0, stream>>>(enc, h, scores, pm, pl, pctx);
    // CD: combine -> context, and scores -> attn_w (no cross-block dependency)
    combine_finish_kernel<<<128 + (Bb * Ss) / 256, 256, 0, stream>>>(pm, pl, pctx, scores,
                                                                     out_ctx, out_attn);
}

// Round 8
// 60.411 us; speedup vs baseline: 2.1143x; 1.0246x over previous
//
#include <hip/hip_runtime.h>
#include <math.h>

// Problem constants (fixed by the reference setup)
constexpr int Bb = 32;
constexpr int Ss = 2048;
constexpr int Hh = 1024;
constexpr int SC = 128;                // s-rows per block in fused kernel
constexpr int CPB = Ss / SC;           // 16 chunks per batch
constexpr int NBLK = Bb * CPB;         // 512 blocks (2 blocks/CU, one round)

// ---------------- Kernel A: h = hidden @ W_in^T ----------------
// Block = (output index i, group of 4 batches). i = blk & 1023 so the 8 blocks
// sharing W row i are 1024 apart -> same XCD -> W row fetched from HBM once.
__global__ __launch_bounds__(256) void gemv_h_kernel(const float* __restrict__ hidden,
                                                     const float* __restrict__ W,
                                                     float* __restrict__ h)
{
    int tid  = threadIdx.x;
    int wave = tid >> 6;
    int lane = tid & 63;
    int i  = blockIdx.x & (Hh - 1);    // 0..1023
    int bg = blockIdx.x >> 10;         // 0..7
    int b  = bg * 4 + wave;            // 0..31
    const float4* wr = reinterpret_cast<const float4*>(W + (size_t)i * Hh);
    const float4* hd = reinterpret_cast<const float4*>(hidden + (size_t)b * Hh);
    float d = 0.f;
#pragma unroll
    for (int k = 0; k < 4; ++k) {
        float4 wv = wr[lane + 64 * k];
        float4 hv = hd[lane + 64 * k];
        d += wv.x * hv.x + wv.y * hv.y + wv.z * hv.z + wv.w * hv.w;
    }
#pragma unroll
    for (int off = 32; off > 0; off >>= 1) d += __shfl_xor(d, off, 64);
    if (lane == 0) h[(size_t)b * Hh + i] = d;
}

// ---------------- Kernel B: fused scores + online softmax + partial context ----
// Block = (batch b, chunk of SC=128 rows). 4 waves x 32 rows = 16 pairs/wave.
// FOUR-deep pair rotation (ev0..ev3, 32 VGPR each): loads for pair p are
// issued 3 COMP-phases (~600-750 cyc) before their use, covering most of the
// ~900-cyc HBM latency inside a single wave; the 2nd wave/SIMD covers the
// rest. Natural VGPR (~190) -> 2 waves/SIMD, no spills (R6 lesson: never cap
// below the live set).
__global__ __launch_bounds__(256) void attn_partial_kernel(const float* __restrict__ enc,
                                                           const float* __restrict__ h,
                                                           float* __restrict__ scores,
                                                           float* __restrict__ pm,
                                                           float* __restrict__ pl,
                                                           float* __restrict__ pctx)
{
    int blk   = blockIdx.x;           // 0..NBLK-1
    int b     = blk >> 4;             // / CPB (CPB = 16)
    int chunk = blk & (CPB - 1);
    int s0    = chunk * SC;
    int tid   = threadIdx.x;
    int wave  = tid >> 6;
    int lane  = tid & 63;

    // h fragment for this lane (elements 4*lane + 256*k)
    float4 hf[4];
    const float4* h4 = reinterpret_cast<const float4*>(h + (size_t)b * Hh);
#pragma unroll
    for (int k = 0; k < 4; ++k) hf[k] = h4[lane + 64 * k];

    float m = -INFINITY;
    float l = 0.f;
    float4 ctx[4];
#pragma unroll
    for (int k = 0; k < 4; ++k) ctx[k] = make_float4(0.f, 0.f, 0.f, 0.f);

    const float4* ebase = reinterpret_cast<const float4*>(enc + ((size_t)b * Ss + s0 + wave * 32) * Hh);

#define LOADP(EV, P)                                                        \
    {                                                                       \
        _Pragma("unroll")                                                   \
        for (int r = 0; r < 2; ++r) {                                       \
            const float4* e4 = ebase + (size_t)((P) * 2 + r) * (Hh / 4);    \
            _Pragma("unroll")                                               \
            for (int k = 0; k < 4; ++k) EV[r][k] = e4[lane + 64 * k];       \
        }                                                                   \
    }

#define COMPP(EV, P)                                                        \
    {                                                                       \
        float d0 = 0.f, d1 = 0.f;                                           \
        _Pragma("unroll")                                                   \
        for (int k = 0; k < 4; ++k) {                                       \
            d0 += EV[0][k].x * hf[k].x + EV[0][k].y * hf[k].y +             \
                  EV[0][k].z * hf[k].z + EV[0][k].w * hf[k].w;              \
            d1 += EV[1][k].x * hf[k].x + EV[1][k].y * hf[k].y +             \
                  EV[1][k].z * hf[k].z + EV[1][k].w * hf[k].w;              \
        }                                                                   \
        _Pragma("unroll")                                                   \
        for (int off = 32; off > 0; off >>= 1) {                            \
            d0 += __shfl_xor(d0, off, 64);                                  \
            d1 += __shfl_xor(d1, off, 64);                                  \
        }                                                                   \
        if (lane == 0) {                                                    \
            *reinterpret_cast<float2*>(scores + (size_t)b * Ss + s0 +       \
                                       wave * 32 + 2 * (P)) =               \
                make_float2(d0, d1);                                        \
        }                                                                   \
        float mn = fmaxf(fmaxf(d0, d1), m);                                 \
        if (mn > m) {                                                       \
            float c = __expf(m - mn);                                       \
            l *= c;                                                         \
            _Pragma("unroll")                                               \
            for (int k = 0; k < 4; ++k) {                                   \
                ctx[k].x *= c; ctx[k].y *= c; ctx[k].z *= c; ctx[k].w *= c; \
            }                                                               \
            m = mn;                                                         \
        }                                                                   \
        float p0 = __expf(d0 - m);                                          \
        float p1 = __expf(d1 - m);                                          \
        l += p0 + p1;                                                       \
        _Pragma("unroll")                                                   \
        for (int k = 0; k < 4; ++k) {                                       \
            ctx[k].x += p0 * EV[0][k].x + p1 * EV[1][k].x;                  \
            ctx[k].y += p0 * EV[0][k].y + p1 * EV[1][k].y;                  \
            ctx[k].z += p0 * EV[0][k].z + p1 * EV[1][k].z;                  \
            ctx[k].w += p0 * EV[0][k].w + p1 * EV[1][k].w;                  \
        }                                                                   \
    }

    float4 ev0[2][4], ev1[2][4], ev2[2][4], ev3[2][4];
    // 4-deep rotation over 16 pairs: issue distance = 3 COMP phases.
    LOADP(ev0, 0); LOADP(ev1, 1); LOADP(ev2, 2);
#pragma unroll 1
    for (int qq = 0; qq < 3; ++qq) {
        int p4 = qq * 4;
        LOADP(ev3, p4 + 3); COMPP(ev0, p4);
        LOADP(ev0, p4 + 4); COMPP(ev1, p4 + 1);
        LOADP(ev1, p4 + 5); COMPP(ev2, p4 + 2);
        LOADP(ev2, p4 + 6); COMPP(ev3, p4 + 3);
    }
    LOADP(ev3, 15);
    COMPP(ev0, 12); COMPP(ev1, 13); COMPP(ev2, 14); COMPP(ev3, 15);
#undef LOADP
#undef COMPP

    // intra-block combine across 4 waves via LDS
    __shared__ float lds_ctx[4][Hh];   // 16 KiB
    __shared__ float lds_m[4], lds_l[4];
    float4* ldsrow = reinterpret_cast<float4*>(lds_ctx[wave]);
#pragma unroll
    for (int k = 0; k < 4; ++k) ldsrow[64 * k + lane] = ctx[k];
    if (lane == 0) { lds_m[wave] = m; lds_l[wave] = l; }
    __syncthreads();

    float M = fmaxf(fmaxf(lds_m[0], lds_m[1]), fmaxf(lds_m[2], lds_m[3]));
    float L = 0.f;
    float4 acc = make_float4(0.f, 0.f, 0.f, 0.f);
#pragma unroll
    for (int w = 0; w < 4; ++w) {
        float c = __expf(lds_m[w] - M);
        L += c * lds_l[w];
        float4 v = reinterpret_cast<float4*>(lds_ctx[w])[tid];
        acc.x += c * v.x; acc.y += c * v.y; acc.z += c * v.z; acc.w += c * v.w;
    }
    reinterpret_cast<float4*>(pctx + (size_t)blk * Hh)[tid] = acc;
    if (tid == 0) { pm[blk] = M; pl[blk] = L; }
}

// ---------------- Kernel CD: combine partials -> context, scores -> attn_w ----
// Blocks [0,128): combine (b = blk>>2, 256-wide H slice). Blocks [128,384):
// finish attn_w; every thread recomputes (M,L) from pm/pl (L2 broadcast, cheap)
// so there is no cross-block dependency.
__global__ __launch_bounds__(256) void combine_finish_kernel(const float* __restrict__ pm,
                                                             const float* __restrict__ pl,
                                                             const float* __restrict__ pctx,
                                                             const float* __restrict__ scores,
                                                             float* __restrict__ out_ctx,
                                                             float* __restrict__ attn_out)
{
    int blk = blockIdx.x;
    int tid = threadIdx.x;
    if (blk < 128) {
        int b = blk >> 2;
        int col = (blk & 3) * 256 + tid;
        const float* mrow = pm + (size_t)b * CPB;
        const float* lrow = pl + (size_t)b * CPB;
        float M = -INFINITY;
#pragma unroll
        for (int c = 0; c < CPB; ++c) M = fmaxf(M, mrow[c]);
        float e[CPB];
        float L = 0.f;
#pragma unroll
        for (int c = 0; c < CPB; ++c) {
            e[c] = __expf(mrow[c] - M);
            L += e[c] * lrow[c];
        }
        float acc = 0.f;
#pragma unroll 4
        for (int c = 0; c < CPB; ++c)
            acc += e[c] * pctx[((size_t)b * CPB + c) * Hh + col];
        out_ctx[(size_t)b * Hh + col] = acc / L;
    } else {
        int idx = (blk - 128) * 256 + tid;   // 0..B*S-1
        int b = idx >> 11;                   // / S
        const float* mrow = pm + (size_t)b * CPB;
        const float* lrow = pl + (size_t)b * CPB;
        float M = -INFINITY;
#pragma unroll
        for (int c = 0; c < CPB; ++c) M = fmaxf(M, mrow[c]);
        float L = 0.f;
#pragma unroll
        for (int c = 0; c < CPB; ++c) L += __expf(mrow[c] - M) * lrow[c];
        attn_out[idx] = __expf(scores[idx] - M) / L;
    }
}

extern "C" void kernel_launch(void* const* d_in, const int* in_sizes, int n_in,
                              void* d_out, int out_size, void* d_ws, size_t ws_size,
                              hipStream_t stream) {
    const float* hidden = (const float*)d_in[0];   // [B,H]
    const float* enc    = (const float*)d_in[1];   // [B,S,H]
    const float* W_in   = (const float*)d_in[2];   // [H,H]

    float* out_ctx  = (float*)d_out;               // [B,H]   context first
    float* out_attn = (float*)d_out + Bb * Hh;     // [B,S]

    float* ws     = (float*)d_ws;
    float* h      = ws;                            // B*H      = 32768
    float* scores = ws + 32768;                    // B*S      = 65536
    float* pm     = ws + 98304;                    // NBLK     = 512
    float* pl     = ws + 98816;                    // NBLK     = 512
    float* pctx   = ws + 99328;                    // NBLK*H   = 524288
    (void)in_sizes; (void)n_in; (void)out_size; (void)ws_size;

    // A: h = hidden @ W_in^T   (XCD-local W-row reuse)
    gemv_h_kernel<<<Hh * (Bb / 4), 256, 0, stream>>>(hidden, W_in, h);
    // B: fused scores + online softmax + partial context (single enc pass,
    //    4-deep pair rotation, distance-3 prefetch, 2 waves/SIMD)
    attn_partial_kernel<<<NBLK, 256, 0, stream>>>(enc, h, scores, pm, pl, pctx);
    // CD: combine -> context, and scores -> attn_w (no cross-block dependency)
    combine_finish_kernel<<<128 + (Bb * Ss) / 256, 256, 0, stream>>>(pm, pl, pctx, scores,
                                                                     out_ctx, out_attn);
}